// Round 1
// baseline (134.355 us; speedup 1.0000x reference)
//
#include <hip/hip_runtime.h>
#include <math.h>

// ExtrudeNet fused kernel for MI355X (gfx950).
// B=4, M=2048 points, K=64 primitives, C=64, NSEG=4, SAMPLE_RATE=16 -> S=64 curve samples.
// Inputs (float32): pts (B,M,3), pp (B,28,K), Wint (B,K,C), Uw (B,C), is_training (int, always 1).
// Output (float32, concatenated): occupancies (B,M) | primitive_sdf (B,M,K) | inter (B,M,C) | support (B,M,K).

#define NB 4
#define NM 2048
#define NK 64
#define NC 64
#define NS 64
#define PPB 4   // points per 256-thread block (1 wave per point)

// Offsets into flat output
#define OCC_OFF   0
#define SDF_OFF   8192        // NB*NM
#define INTER_OFF 532480      // 8192 + 524288
#define SUP_OFF   1056768     // 8192 + 2*524288

// theta = 2*pi/16 + atan(tan(2*pi/16)/3) = 0.5299027864949896 (double-accurate)
#define CT 0.86285621096f     // cos(theta)
#define ST 0.50544946275f     // sin(theta)

__global__ __launch_bounds__(256) void extrude_net_kernel(
    const float* __restrict__ pts,
    const float* __restrict__ pp,
    const float* __restrict__ Wint,
    const float* __restrict__ Uw,
    float* __restrict__ out)
{
    // SoA curve layout: read pattern in phase 1 is (uniform s, lane k) -> bank k%32,
    // 2 lanes/bank = conflict-free on gfx950 (m136).
    __shared__ float s_cx[NS][NK];   // 16 KB
    __shared__ float s_cy[NS][NK];   // 16 KB
    __shared__ float s_occ[PPB][NK]; // 1 KB

    const int tid  = threadIdx.x;
    const int lane = tid & 63;
    const int wv   = tid >> 6;                 // wave id in block = point slot
    const int gpt  = blockIdx.x * PPB + wv;    // global point index in [0, B*M)
    const int b    = gpt >> 11;                // / 2048
    const float* __restrict__ ppb = pp + b * (28 * NK);

    // ---------- Phase 0: rational bezier curve samples for all K primitives of batch b ----------
    {
        const int k    = lane;
        const int seg  = wv;             // 0..3 (NSEG), wave-uniform
        const int nseg = (seg + 1) & 3;
        const float r0 = fabsf(ppb[(8 + seg * 3 + 0) * NK + k]);
        const float r1 = fabsf(ppb[(8 + seg * 3 + 1) * NK + k]);
        const float r2 = fabsf(ppb[(8 + seg * 3 + 2) * NK + k]);
        const float rn = fabsf(ppb[(8 + nseg * 3 + 0) * NK + k]);
        const float w1 = fabsf(ppb[(20 + seg * 2 + 0) * NK + k]);
        const float w2 = fabsf(ppb[(20 + seg * 2 + 1) * NK + k]);

        // cos/sin of control radians, per segment (rotations of (CT,ST) by seg*90deg)
        const float c0x[4] = { 1.f, 0.f, -1.f,  0.f };
        const float c0y[4] = { 0.f, 1.f,  0.f, -1.f };
        const float c1x[4] = {  CT, -ST, -CT,  ST };
        const float c1y[4] = {  ST,  CT, -ST, -CT };
        const float c2x[4] = {  ST, -CT, -ST,  CT };
        const float c2y[4] = {  CT,  ST, -CT, -ST };

        const float P0x = c0x[seg] * r0,  P0y = c0y[seg] * r0;
        const float P1x = c1x[seg] * r1,  P1y = c1y[seg] * r1;
        const float P2x = c2x[seg] * r2,  P2y = c2y[seg] * r2;
        const float P3x = c0x[nseg] * rn, P3y = c0y[nseg] * rn;

        #pragma unroll
        for (int j = 0; j < 16; ++j) {
            const float t  = (float)j * 0.0625f;   // linspace(0,1,16,endpoint=False)
            const float u  = 1.f - t;
            const float b0 = u * u * u;
            const float b1 = 3.f * u * u * t;
            const float b2 = 3.f * u * t * t;
            const float b3 = t * t * t;
            const float wb1 = w1 * b1, wb2 = w2 * b2;
            const float inv = 1.f / (b0 + wb1 + wb2 + b3);
            const int s = seg * 16 + j;
            s_cx[s][k] = (P0x * b0 + P1x * wb1 + P2x * wb2 + P3x * b3) * inv;
            s_cy[s][k] = (P0y * b0 + P1y * wb1 + P2y * wb2 + P3y * b3) * inv;
        }
    }
    __syncthreads();

    // ---------- Phase 1: per-primitive SDF; wave = one point, lane = primitive k ----------
    const float ptx = pts[gpt * 3 + 0];
    const float pty = pts[gpt * 3 + 1];
    const float ptz = pts[gpt * 3 + 2];
    {
        const int k = lane;
        const float q0 = ppb[0 * NK + k], q1 = ppb[1 * NK + k];
        const float q2 = ppb[2 * NK + k], q3 = ppb[3 * NK + k];
        const float trx = ppb[4 * NK + k], try_ = ppb[5 * NK + k], trz = ppb[6 * NK + k];
        const float h   = ppb[7 * NK + k];

        const float px = ptx - trx, py = pty - try_, pz = ptz - trz;
        const float inv = 1.f / sqrtf(q0 * q0 + q1 * q1 + q2 * q2 + q3 * q3 + 1e-8f);
        const float w  = q0 * inv;
        const float vx = -q1 * inv, vy = -q2 * inv, vz = -q3 * inv;
        // rotate by conjugate: pl = p + w*t2 + cross(v, t2), t2 = 2*cross(v, p)
        const float t2x = 2.f * (vy * pz - vz * py);
        const float t2y = 2.f * (vz * px - vx * pz);
        const float t2z = 2.f * (vx * py - vy * px);
        const float plx = px + w * t2x + (vy * t2z - vz * t2y);
        const float ply = py + w * t2y + (vz * t2x - vx * t2z);
        const float plz = pz + w * t2z + (vx * t2y - vy * t2x);

        float rx = s_cx[0][k] - plx;
        float ry = s_cy[0][k] - ply;
        float wind  = 0.f;
        float d2min = 3.4e38f;
        #pragma unroll 4
        for (int s = 0; s < NS; ++s) {
            const int sn = (s + 1) & 63;
            const float nx = s_cx[sn][k] - plx;
            const float ny = s_cy[sn][k] - ply;
            const float cr = rx * ny - ry * nx;
            const float dt = rx * nx + ry * ny;
            wind += atan2f(cr, dt);
            d2min = fminf(d2min, rx * rx + ry * ry);
            rx = nx; ry = ny;
        }
        const float dmin    = sqrtf(d2min + 1e-12f);
        const float winding = wind * 0.15915494309189535f;  // /(2*pi)
        const float sdf2d   = (fabsf(winding) > 0.5f) ? -dmin : dmin;
        const float dz      = fabsf(plz) - fabsf(h);
        const float mx      = fmaxf(sdf2d, dz);
        const float e1      = fmaxf(sdf2d, 0.f);
        const float e2      = fmaxf(dz, 0.f);
        const float sdf     = fminf(mx, 0.f) + sqrtf(e1 * e1 + e2 * e2 + 1e-12f);

        out[SDF_OFF + gpt * NK + k] = sdf;
        out[SUP_OFF + gpt * NK + k] = dmin;
        s_occ[wv][k] = 1.f / (1.f + expf(150.f * sdf));   // sigmoid(-sdf*150)
    }
    __syncthreads();

    // ---------- Phase 2: intersection (online softmax over k) + union (wave softmax over c) ----------
    {
        const int c = lane;
        const float* __restrict__ Wb = Wint + b * (NK * NC);
        float mrun = -3.0e38f, srun = 0.f, trun = 0.f;
        #pragma unroll 4
        for (int kk = 0; kk < NK; ++kk) {
            const float om   = 1.f - s_occ[wv][kk];       // broadcast LDS read
            const float pre  = 1.f - Wb[kk * NC + c] * om;
            const float l    = -40.f * pre;
            const float mnew = fmaxf(mrun, l);
            const float ea   = expf(mrun - mnew);
            const float eb   = expf(l - mnew);
            srun = srun * ea + eb;
            trun = trun * ea + eb * pre;
            mrun = mnew;
        }
        const float inter = trun / srun;
        out[INTER_OFF + gpt * NC + c] = inter;

        const float pu = Uw[b * NC + c] * inter;
        float umax = pu;
        #pragma unroll
        for (int off = 32; off > 0; off >>= 1)
            umax = fmaxf(umax, __shfl_xor(umax, off, 64));
        const float e = expf(40.f * (pu - umax));
        float s1 = e, s2 = e * pu;
        #pragma unroll
        for (int off = 32; off > 0; off >>= 1) {
            s1 += __shfl_xor(s1, off, 64);
            s2 += __shfl_xor(s2, off, 64);
        }
        if (lane == 0) out[OCC_OFF + gpt] = s2 / s1;
    }
}

extern "C" void kernel_launch(void* const* d_in, const int* in_sizes, int n_in,
                              void* d_out, int out_size, void* d_ws, size_t ws_size,
                              hipStream_t stream) {
    const float* pts  = (const float*)d_in[0];
    const float* pp   = (const float*)d_in[1];
    const float* Wint = (const float*)d_in[2];
    const float* Uw   = (const float*)d_in[3];
    // d_in[4] = is_training (always 1 in this harness) -> training path hardcoded.
    float* out = (float*)d_out;

    const int n_points = NB * NM;              // 8192
    const int grid     = n_points / PPB;       // 2048 blocks x 256 threads
    extrude_net_kernel<<<grid, 256, 0, stream>>>(pts, pp, Wint, Uw, out);
}

// Round 2
// 91.451 us; speedup vs baseline: 1.4691x; 1.4691x over previous
//
#include <hip/hip_runtime.h>
#include <math.h>

// ExtrudeNet fused kernel for MI355X (gfx950) — round 2.
// B=4, M=2048 points, K=64 primitives, C=64, NSEG=4, SAMPLE_RATE=16 -> S=64 curve samples.
// Inputs (float32): pts (B,M,3), pp (B,28,K), Wint (B,K,C), Uw (B,C), is_training (int, always 1).
// Output (float32, concatenated): occupancies (B,M) | primitive_sdf (B,M,K) | inter (B,M,C) | support (B,M,K).
//
// R2 changes vs R1 (R1: 85 us, VALUBusy 97%, atan2f-dominated):
//  - winding via integer crossing rule (Sunday) instead of 64x atan2f:
//    sum(atan2) is exactly 2*pi*wn for closed polygons, so |winding|>0.5 <=> wn != 0.
//  - phase-2 online softmax without max tracking (logits in [-40,0] -> exp2f safe range),
//    LDS stores om = 1-occ directly, native exp2f.
//  - curve table as float2 -> ds_read_b64 (1 LDS op/iter), amdgcn_rcpf in phase 0.

#define NB 4
#define NM 2048
#define NK 64
#define NC 64
#define NS 64
#define PPB 4   // points per 256-thread block (1 wave per point)

// Offsets into flat output
#define OCC_OFF   0
#define SDF_OFF   8192        // NB*NM
#define INTER_OFF 532480      // 8192 + 524288
#define SUP_OFF   1056768     // 8192 + 2*524288

// theta = 2*pi/16 + atan(tan(2*pi/16)/3) = 0.5299027864949896 (double-accurate)
#define CT 0.86285621096f     // cos(theta)
#define ST 0.50544946275f     // sin(theta)

#define L2E_40  57.70780163555852f   // 40 * log2(e)
#define L2E_150 216.40425613334447f  // 150 * log2(e)

__global__ __launch_bounds__(256) void extrude_net_kernel(
    const float* __restrict__ pts,
    const float* __restrict__ pp,
    const float* __restrict__ Wint,
    const float* __restrict__ Uw,
    float* __restrict__ out)
{
    // Curve table interleaved as float2: phase-1 read is (uniform s, lane k) ->
    // 8B/lane, 2 lanes/bank aliasing = conflict-free on gfx950 (m136).
    __shared__ float2 s_curve[NS][NK];  // 32 KB
    __shared__ float  s_om[PPB][NK];    // 1 KB : om = 1 - occ = sigmoid(+150*sdf)

    const int tid  = threadIdx.x;
    const int lane = tid & 63;
    const int wv   = tid >> 6;                 // wave id in block = point slot
    const int gpt  = blockIdx.x * PPB + wv;    // global point index in [0, B*M)
    const int b    = gpt >> 11;                // / 2048
    const float* __restrict__ ppb = pp + b * (28 * NK);

    // ---------- Phase 0: rational bezier curve samples for all K primitives of batch b ----------
    {
        const int k    = lane;
        const int seg  = wv;             // 0..3 (NSEG), wave-uniform
        const int nseg = (seg + 1) & 3;
        const float r0 = fabsf(ppb[(8 + seg * 3 + 0) * NK + k]);
        const float r1 = fabsf(ppb[(8 + seg * 3 + 1) * NK + k]);
        const float r2 = fabsf(ppb[(8 + seg * 3 + 2) * NK + k]);
        const float rn = fabsf(ppb[(8 + nseg * 3 + 0) * NK + k]);
        const float w1 = fabsf(ppb[(20 + seg * 2 + 0) * NK + k]);
        const float w2 = fabsf(ppb[(20 + seg * 2 + 1) * NK + k]);

        // cos/sin of control radians, per segment (rotations of (CT,ST) by seg*90deg)
        const float c0x[4] = { 1.f, 0.f, -1.f,  0.f };
        const float c0y[4] = { 0.f, 1.f,  0.f, -1.f };
        const float c1x[4] = {  CT, -ST, -CT,  ST };
        const float c1y[4] = {  ST,  CT, -ST, -CT };
        const float c2x[4] = {  ST, -CT, -ST,  CT };
        const float c2y[4] = {  CT,  ST, -CT, -ST };

        const float P0x = c0x[seg] * r0,  P0y = c0y[seg] * r0;
        const float P1x = c1x[seg] * r1,  P1y = c1y[seg] * r1;
        const float P2x = c2x[seg] * r2,  P2y = c2y[seg] * r2;
        const float P3x = c0x[nseg] * rn, P3y = c0y[nseg] * rn;

        #pragma unroll
        for (int j = 0; j < 16; ++j) {
            const float t  = (float)j * 0.0625f;   // compile-time constants after unroll
            const float u  = 1.f - t;
            const float b0 = u * u * u;
            const float b1 = 3.f * u * u * t;
            const float b2 = 3.f * u * t * t;
            const float b3 = t * t * t;
            const float wb1 = w1 * b1, wb2 = w2 * b2;
            const float inv = __builtin_amdgcn_rcpf(b0 + wb1 + wb2 + b3);
            const int s = seg * 16 + j;
            s_curve[s][k] = make_float2(
                (P0x * b0 + P1x * wb1 + P2x * wb2 + P3x * b3) * inv,
                (P0y * b0 + P1y * wb1 + P2y * wb2 + P3y * b3) * inv);
        }
    }
    __syncthreads();

    // ---------- Phase 1: per-primitive SDF; wave = one point, lane = primitive k ----------
    const float ptx = pts[gpt * 3 + 0];
    const float pty = pts[gpt * 3 + 1];
    const float ptz = pts[gpt * 3 + 2];
    {
        const int k = lane;
        const float q0 = ppb[0 * NK + k], q1 = ppb[1 * NK + k];
        const float q2 = ppb[2 * NK + k], q3 = ppb[3 * NK + k];
        const float trx = ppb[4 * NK + k], try_ = ppb[5 * NK + k], trz = ppb[6 * NK + k];
        const float h   = ppb[7 * NK + k];

        const float px = ptx - trx, py = pty - try_, pz = ptz - trz;
        const float inv = 1.f / sqrtf(q0 * q0 + q1 * q1 + q2 * q2 + q3 * q3 + 1e-8f);
        const float w  = q0 * inv;
        const float vx = -q1 * inv, vy = -q2 * inv, vz = -q3 * inv;
        // rotate by conjugate: pl = p + w*t2 + cross(v, t2), t2 = 2*cross(v, p)
        const float t2x = 2.f * (vy * pz - vz * py);
        const float t2y = 2.f * (vz * px - vx * pz);
        const float t2z = 2.f * (vx * py - vy * px);
        const float plx = px + w * t2x + (vy * t2z - vz * t2y);
        const float ply = py + w * t2y + (vz * t2x - vx * t2z);
        const float plz = pz + w * t2z + (vx * t2y - vy * t2x);

        float2 c0 = s_curve[0][k];
        float rx = c0.x - plx;
        float ry = c0.y - ply;
        int   wn    = 0;
        float d2min = 3.4e38f;
        #pragma unroll 8
        for (int s = 0; s < NS; ++s) {
            const int sn = (s + 1) & 63;
            const float2 cn = s_curve[sn][k];
            const float nx = cn.x - plx;
            const float ny = cn.y - ply;
            // Sunday crossing rule: cross(rel, nxt) == isLeft(V0,V1,P)
            const float cr = rx * ny - ry * nx;
            wn += (ry <= 0.f && ny >  0.f && cr > 0.f) ? 1 : 0;
            wn -= (ry >  0.f && ny <= 0.f && cr < 0.f) ? 1 : 0;
            d2min = fminf(d2min, rx * rx + ry * ry);
            rx = nx; ry = ny;
        }
        const float dmin  = sqrtf(d2min + 1e-12f);
        // sum(atan2) over a closed polygon = 2*pi*wn exactly; |winding|>0.5 <=> wn != 0
        const float sdf2d = (wn != 0) ? -dmin : dmin;
        const float dz    = fabsf(plz) - fabsf(h);
        const float mx    = fmaxf(sdf2d, dz);
        const float e1    = fmaxf(sdf2d, 0.f);
        const float e2    = fmaxf(dz, 0.f);
        const float sdf   = fminf(mx, 0.f) + sqrtf(e1 * e1 + e2 * e2 + 1e-12f);

        out[SDF_OFF + gpt * NK + k] = sdf;
        out[SUP_OFF + gpt * NK + k] = dmin;
        // om = 1 - sigmoid(-150*sdf) = sigmoid(+150*sdf)
        s_om[wv][k] = 1.f / (1.f + exp2f(-sdf * L2E_150));
    }
    __syncthreads();

    // ---------- Phase 2: intersection (softmax over k, no max tracking needed:
    // pre in [0,1] -> logits -40*pre in [-40,0], exp2f range [2^-57.7, 1] is normal) ----------
    {
        const int c = lane;
        const float* __restrict__ Wb = Wint + b * (NK * NC);
        float srun = 0.f, trun = 0.f;
        #pragma unroll 8
        for (int kk = 0; kk < NK; ++kk) {
            const float om  = s_om[wv][kk];                  // broadcast LDS read
            const float pre = fmaf(-Wb[kk * NC + c], om, 1.f);
            const float e   = exp2f(pre * -L2E_40);
            srun += e;
            trun = fmaf(e, pre, trun);
        }
        const float inter = trun / srun;
        out[INTER_OFF + gpt * NC + c] = inter;

        // Union: softmax(pu*40)-weighted sum across the wave's 64 lanes
        const float pu = Uw[b * NC + c] * inter;
        float umax = pu;
        #pragma unroll
        for (int off = 32; off > 0; off >>= 1)
            umax = fmaxf(umax, __shfl_xor(umax, off, 64));
        const float e = exp2f((pu - umax) * L2E_40);
        float s1 = e, s2 = e * pu;
        #pragma unroll
        for (int off = 32; off > 0; off >>= 1) {
            s1 += __shfl_xor(s1, off, 64);
            s2 += __shfl_xor(s2, off, 64);
        }
        if (lane == 0) out[OCC_OFF + gpt] = s2 / s1;
    }
}

extern "C" void kernel_launch(void* const* d_in, const int* in_sizes, int n_in,
                              void* d_out, int out_size, void* d_ws, size_t ws_size,
                              hipStream_t stream) {
    const float* pts  = (const float*)d_in[0];
    const float* pp   = (const float*)d_in[1];
    const float* Wint = (const float*)d_in[2];
    const float* Uw   = (const float*)d_in[3];
    // d_in[4] = is_training (always 1 in this harness) -> training path hardcoded.
    float* out = (float*)d_out;

    const int n_points = NB * NM;              // 8192
    const int grid     = n_points / PPB;       // 2048 blocks x 256 threads
    extrude_net_kernel<<<grid, 256, 0, stream>>>(pts, pp, Wint, Uw, out);
}